// Round 5
// baseline (325.628 us; speedup 1.0000x reference)
//
#include <hip/hip_runtime.h>
#include <cstdint>

// ---------------------------------------------------------------------------
// AttentionAIC: dual-stream QKV proj + per-head RMSNorm + joint SDPA + out-proj
// B=1, S=2048, S_enc=256, D=1536, H=24, HD=64, T=2304.
// Context output discarded -> skip add_q_proj, encoder q-rows, to_add_out.
// R5: (a) flash split-K x2: q-tile 32, grid 1536, LDS 36KB -> 4 blocks/CU
//     (R4 was grid-limited to 3 blocks/CU, occupancy 31.6%). Per-pair dbuf
//     K/V tiles, 1 barrier/iter, cross-pair (o,l) LDS combine at end.
// (b) GEMM BK=64 (two kh sub-steps, frag regs reused -> VGPR flat): halves
//     barrier count; XOR-chunk swizzle for the now-128B rows.
// ---------------------------------------------------------------------------

typedef __attribute__((ext_vector_type(8))) short s16x8;   // 8 x bf16
typedef __attribute__((ext_vector_type(4))) float f32x4;

#define LOG2E 1.4426950408889634f

__device__ __forceinline__ short f2bf(float f) {          // RNE (epilogues)
  union { float f; uint32_t u; } v; v.f = f;
  uint32_t r = v.u + 0x7FFFu + ((v.u >> 16) & 1u);
  return (short)(r >> 16);
}
__device__ __forceinline__ short f2bf_fast(float f) {     // round-to-nearest
  union { float f; uint32_t u; } v; v.f = f;
  return (short)((v.u + 0x8000u) >> 16);
}

typedef uint32_t __attribute__((address_space(1)))* gas_u32;
typedef uint32_t __attribute__((address_space(3)))* las_u32;

// async global->LDS, 16B per lane; dest must be wave-uniform base + lane*16
__device__ __forceinline__ void gload_lds16(const short* g, short* l) {
  __builtin_amdgcn_global_load_lds((gas_u32)(g), (las_u32)(l), 16, 0, 0);
}

// ---------------------------------------------------------------------------
// fp32 -> bf16 conversion (8 segments in one launch)
// ---------------------------------------------------------------------------
struct CvtSeg { const float* src; short* dst; int n4; };
struct CvtArgs { CvtSeg s[8]; };

__global__ __launch_bounds__(256) void cvt_bf16_kernel(CvtArgs a) {
  const int stride = gridDim.x * blockDim.x;
  const int tid = blockIdx.x * blockDim.x + threadIdx.x;
  for (int i = 0; i < 8; ++i) {
    const float4* src = (const float4*)a.s[i].src;
    short* dst = a.s[i].dst;
    const int n4 = a.s[i].n4;
    for (int j = tid; j < n4; j += stride) {
      float4 v = src[j];
      short4 o;
      o.x = f2bf(v.x); o.y = f2bf(v.y); o.z = f2bf(v.z); o.w = f2bf(v.w);
      *(short4*)(dst + (size_t)j * 4) = o;
    }
  }
}

// ---------------------------------------------------------------------------
// GEMM: C[M,1536] = A[M,1536] @ W[1536,1536]^T (+bias) with fused epilogues
// 128x128 tile, BK=64 (2 kh sub-steps), 4 waves (2x2), wave = 64x64 via 4x4
// of 16x16x32 MFMA. Rows are 64 shorts (128B): XOR-chunk swizzle (8 chunks,
// pos = c ^ (row&7)) staged at the source address keeps b128 reads 2-way.
// ---------------------------------------------------------------------------
enum { MODE_Q = 0, MODE_K = 1, MODE_V = 2, MODE_OUT = 3 };

struct GemmCfg {
  const short* A;      // [M,1536] bf16
  const short* W;      // [1536,1536] bf16, row-major [N][K]
  const float* bias;   // [1536] fp32
  const float* normw;  // [64] fp32 (Q/K modes)
  void* dst;
  int toff;            // t offset for K/V (0 hidden, 2048 encoder)
  int mode;
  int mtiles;          // # of 128-row M tiles (16 hidden, 2 encoder)
};
struct GemmArgs { GemmCfg c[5]; };

__global__ __launch_bounds__(256) void proj_gemm_kernel(GemmArgs args) {
  const GemmCfg cfg = args.c[blockIdx.z];
  if ((int)blockIdx.y >= cfg.mtiles) return;
  constexpr int K = 1536;
  __shared__ short As[8192];  // [128][64], chunk-swizzled
  __shared__ short Bs[8192];
  const int t = threadIdx.x;
  const int lane = t & 63;
  const int wave = t >> 6;
  const int l16 = lane & 15;
  const int quad = lane >> 4;
  const int wm = wave >> 1;
  const int wn = wave & 1;

  const short* __restrict__ Ag = cfg.A + (size_t)(blockIdx.y * 128) * K;
  const short* __restrict__ Wg = cfg.W + (size_t)(blockIdx.x * 128) * K;
  // staging: 4 calls per matrix per iter; call j covers rows j*32..j*32+31
  const int srow = t >> 3;            // 0..31
  const int cpos = t & 7;             // chunk position in LDS row
  const int srcc = cpos ^ (srow & 7); // source chunk (XOR swizzle)

  const f32x4 z4 = {0.f, 0.f, 0.f, 0.f};
  f32x4 acc[4][4];
#pragma unroll
  for (int i = 0; i < 4; ++i) {
#pragma unroll
    for (int j = 0; j < 4; ++j) acc[i][j] = z4;
  }

  for (int k0 = 0; k0 < K; k0 += 64) {
#pragma unroll
    for (int j = 0; j < 4; ++j) {
      const size_t roff = (size_t)(j * 32 + srow) * K + k0 + srcc * 8;
      gload_lds16(Ag + roff, As + j * 2048 + t * 8);
      gload_lds16(Wg + roff, Bs + j * 2048 + t * 8);
    }
    __syncthreads();
#pragma unroll
    for (int kh = 0; kh < 2; ++kh) {
      s16x8 af[4], bfr[4];
#pragma unroll
      for (int i = 0; i < 4; ++i) {
        int pos = (kh * 4 + quad) ^ (l16 & 7);
        af[i]  = *(const s16x8*)(As + (wm * 64 + i * 16 + l16) * 64 + pos * 8);
        bfr[i] = *(const s16x8*)(Bs + (wn * 64 + i * 16 + l16) * 64 + pos * 8);
      }
#pragma unroll
      for (int mi = 0; mi < 4; ++mi) {
#pragma unroll
        for (int ni = 0; ni < 4; ++ni)
          acc[mi][ni] = __builtin_amdgcn_mfma_f32_16x16x32_bf16(af[mi], bfr[ni], acc[mi][ni], 0, 0, 0);
      }
    }
    __syncthreads();
  }

  // epilogue: C/D layout col=lane&15, row=quad*4+reg
  const int nbase = blockIdx.x * 128 + wn * 64;   // 64-aligned -> one head/wave
  const int mbase = blockIdx.y * 128 + wm * 64;
  const int mode = cfg.mode;
  const int h = nbase >> 6;

  float biasv[4], nwv[4];
#pragma unroll
  for (int ni = 0; ni < 4; ++ni) {
    int col = nbase + ni * 16 + l16;
    biasv[ni] = cfg.bias[col];
    nwv[ni] = (mode == MODE_Q || mode == MODE_K) ? cfg.normw[col & 63] : 0.f;
  }

#pragma unroll
  for (int mi = 0; mi < 4; ++mi) {
    float vv[4][4];
#pragma unroll
    for (int ni = 0; ni < 4; ++ni) {
#pragma unroll
      for (int r = 0; r < 4; ++r) vv[ni][r] = acc[mi][ni][r] + biasv[ni];
    }
    if (mode == MODE_Q || mode == MODE_K) {
      // RMSNorm over the head (this wave's 64 cols): reduce ni then 16 lanes
      float ss[4];
#pragma unroll
      for (int r = 0; r < 4; ++r)
        ss[r] = vv[0][r] * vv[0][r] + vv[1][r] * vv[1][r] +
                vv[2][r] * vv[2][r] + vv[3][r] * vv[3][r];
#pragma unroll
      for (int r = 0; r < 4; ++r) {
        ss[r] += __shfl_xor(ss[r], 1);
        ss[r] += __shfl_xor(ss[r], 2);
        ss[r] += __shfl_xor(ss[r], 4);
        ss[r] += __shfl_xor(ss[r], 8);
        float rs = rsqrtf(ss[r] * (1.0f / 64.0f) + 1e-6f);
#pragma unroll
        for (int ni = 0; ni < 4; ++ni) vv[ni][r] *= rs * nwv[ni];
      }
    }
    const int row0 = mbase + mi * 16 + quad * 4;  // + r
    if (mode == MODE_Q) {
      short* Qd = (short*)cfg.dst;  // [24][2048][64]
#pragma unroll
      for (int ni = 0; ni < 4; ++ni) {
        int d = ni * 16 + l16;
#pragma unroll
        for (int r = 0; r < 4; ++r)
          Qd[((size_t)h * 2048 + row0 + r) * 64 + d] = f2bf(vv[ni][r]);
      }
    } else if (mode == MODE_K) {
      short* Kd = (short*)cfg.dst;  // [24][2304][64]
#pragma unroll
      for (int ni = 0; ni < 4; ++ni) {
        int d = ni * 16 + l16;
#pragma unroll
        for (int r = 0; r < 4; ++r)
          Kd[((size_t)h * 2304 + cfg.toff + row0 + r) * 64 + d] = f2bf(vv[ni][r]);
      }
    } else if (mode == MODE_V) {
      short* Vd = (short*)cfg.dst;  // V^T: [24][64][2304]
#pragma unroll
      for (int ni = 0; ni < 4; ++ni) {
        int d = ni * 16 + l16;
        short4 o4;
        o4.x = f2bf(vv[ni][0]); o4.y = f2bf(vv[ni][1]);
        o4.z = f2bf(vv[ni][2]); o4.w = f2bf(vv[ni][3]);
        *(short4*)(Vd + ((size_t)h * 64 + d) * 2304 + cfg.toff + row0) = o4;
      }
    } else {  // MODE_OUT: fp32 row-major [2048][1536]
      float* Od = (float*)cfg.dst;
#pragma unroll
      for (int ni = 0; ni < 4; ++ni) {
        int col = nbase + ni * 16 + l16;
#pragma unroll
        for (int r = 0; r < 4; ++r)
          Od[(size_t)(row0 + r) * 1536 + col] = vv[ni][r];
      }
    }
  }
}

// ---------------------------------------------------------------------------
// Flash attention v4: split-K x2. Block = (32 q-rows, head); wave w:
// qw = w&1 (16-row half), ks = w>>1 (k-stream: ks*1152..+1152 in 36 x 32-t
// tiles). Each 2-wave pair double-buffers its own 32x64 K tile + 64x32 V^T
// tile via global_load_lds (source XOR-chunk swizzled), 1 barrier/iter.
// No online max (|score|<=8: RMSNormed q,k); l = P @ ones. Cross-pair (o,l)
// combined via LDS at the end. Grid 1536 = 8 XCD * 3 heads * 64 qblk.
// LDS 36864B -> 4 blocks/CU (R4 was grid-capped at 3).
// ---------------------------------------------------------------------------
__global__ __launch_bounds__(256) void flash_kernel(
    const short* __restrict__ Q, const short* __restrict__ Kc,
    const short* __restrict__ VT, const float* __restrict__ mask,
    short* __restrict__ AO) {
  const int b = blockIdx.x;
  const int h = (b & 7) * 3 + ((b >> 3) % 3);
  const int q0 = ((b >> 3) / 3) * 32;
  const int lane = threadIdx.x & 63;
  const int wave = threadIdx.x >> 6;
  const int qw = wave & 1;
  const int ks = wave >> 1;
  const int l16 = lane & 15;
  const int quad = lane >> 4;

  // LDS (shorts): Kt[stream][buf] 4*2048 @0, Vt 4*2048 @8192, P 4*512 @16384
  __shared__ __align__(16) short smem[18432];
  short* Pw = smem + 16384 + wave * 512;

  const short* Kh = Kc + (size_t)h * 2304 * 64;
  const short* Vh = VT + (size_t)h * 64 * 2304;

  // Q fragments: this wave's 16 q-rows
  const short* Qrow = Q + ((size_t)h * 2048 + q0 + qw * 16 + l16) * 64;
  s16x8 aq0 = *(const s16x8*)(Qrow + quad * 8);
  s16x8 aq1 = *(const s16x8*)(Qrow + quad * 8 + 32);

  s16x8 ones;
#pragma unroll
  for (int i = 0; i < 8; ++i) ones[i] = (short)0x3F80;  // bf16 1.0

  const f32x4 z4 = {0.f, 0.f, 0.f, 0.f};
  f32x4 o[4] = {z4, z4, z4, z4};
  f32x4 lacc = z4;
  const float SC = 0.125f * LOG2E;
  const int kbase = ks * 1152;

  auto stage = [&](int it, int buf) {
    const int kb = kbase + it * 32;
    short* kt = smem + (ks * 2 + buf) * 2048;
    short* vt = smem + 8192 + (ks * 2 + buf) * 2048;
#pragma unroll
    for (int c = 0; c < 2; ++c) {
      // K tile [t=32][d=64], 8 chunks/row, pos = cp ^ (t&7)
      int s = c * 128 + qw * 64 + lane;
      int trow = s >> 3, cp = s & 7;
      gload_lds16(Kh + (size_t)(kb + trow) * 64 + (cp ^ (trow & 7)) * 8,
                  kt + c * 1024 + qw * 512 + lane * 8);
      // V^T tile [d=64][t=32], 4 chunks/row, pos = cp ^ ((d>>1)&3)
      int d = s >> 2, cpv = s & 3;
      gload_lds16(Vh + (size_t)d * 2304 + kb + ((cpv ^ ((d >> 1) & 3)) * 8),
                  vt + c * 1024 + qw * 512 + lane * 8);
    }
  };

  stage(0, 0);
  __syncthreads();

  for (int it = 0; it < 36; ++it) {
    const int buf = it & 1;
    if (it < 35) stage(it + 1, buf ^ 1);
    const short* kt = smem + (ks * 2 + buf) * 2048;
    const short* vt = smem + 8192 + (ks * 2 + buf) * 2048;
    const int kb = kbase + it * 32;

    // QK^T -> exp -> P (per-wave swizzled 16x32 tile)
#pragma unroll
    for (int ni = 0; ni < 2; ++ni) {
      const int tt = ni * 16 + l16;
      const short* kr = kt + tt * 64;
      s16x8 bk0 = *(const s16x8*)(kr + ((quad ^ (tt & 7)) << 3));
      s16x8 bk1 = *(const s16x8*)(kr + (((quad + 4) ^ (tt & 7)) << 3));
      f32x4 p0 = __builtin_amdgcn_mfma_f32_16x16x32_bf16(aq0, bk0, z4, 0, 0, 0);
      f32x4 s  = __builtin_amdgcn_mfma_f32_16x16x32_bf16(aq1, bk1, p0, 0, 0, 0);
      float mvl = mask[kb + tt] * LOG2E;
      const int cc = tt >> 3;
#pragma unroll
      for (int rr = 0; rr < 4; ++rr) {
        float pv = __builtin_amdgcn_exp2f(fmaf(s[rr], SC, mvl));
        int prow = quad * 4 + rr;
        Pw[prow * 32 + ((cc ^ ((prow >> 1) & 3)) << 3) + (tt & 7)] = f2bf_fast(pv);
      }
    }
    // P: C-layout -> A-operand (same-wave LDS roundtrip, lgkm-ordered)
    s16x8 ap = *(const s16x8*)(Pw + l16 * 32 + ((quad ^ ((l16 >> 1) & 3)) << 3));
    lacc = __builtin_amdgcn_mfma_f32_16x16x32_bf16(ap, ones, lacc, 0, 0, 0);
#pragma unroll
    for (int ni = 0; ni < 4; ++ni) {
      const int d = ni * 16 + l16;
      s16x8 bv = *(const s16x8*)(vt + d * 32 + ((quad ^ ((d >> 1) & 3)) << 3));
      o[ni] = __builtin_amdgcn_mfma_f32_16x16x32_bf16(ap, bv, o[ni], 0, 0, 0);
    }
    __syncthreads();   // next tile's staging landed during compute
  }

  // cross-pair combine: ks=1 dumps (o,l) -> LDS (reuses K region), ks=0 sums
  f32x4* R = (f32x4*)smem;   // [qw*64+lane][5]
  if (ks == 1) {
    f32x4* Rw = R + (qw * 64 + lane) * 5;
#pragma unroll
    for (int ni = 0; ni < 4; ++ni) Rw[ni] = o[ni];
    Rw[4] = lacc;
  }
  __syncthreads();
  if (ks == 0) {
    const f32x4* Rw = R + (qw * 64 + lane) * 5;
#pragma unroll
    for (int ni = 0; ni < 4; ++ni) o[ni] += Rw[ni];
    lacc += Rw[4];
#pragma unroll
    for (int rr = 0; rr < 4; ++rr) {
      float inv = 1.0f / lacc[rr];
      int tq = q0 + qw * 16 + quad * 4 + rr;
#pragma unroll
      for (int ni = 0; ni < 4; ++ni)
        AO[(size_t)tq * 1536 + h * 64 + ni * 16 + l16] = f2bf(o[ni][rr] * inv);
    }
  }
}

// ---------------------------------------------------------------------------
extern "C" void kernel_launch(void* const* d_in, const int* in_sizes, int n_in,
                              void* d_out, int out_size, void* d_ws, size_t ws_size,
                              hipStream_t stream) {
  (void)in_sizes; (void)n_in; (void)out_size; (void)ws_size;
  const float* hidden = (const float*)d_in[0];
  const float* enc    = (const float*)d_in[1];
  const float* amask  = (const float*)d_in[2];
  const float* wq  = (const float*)d_in[3];  const float* bq  = (const float*)d_in[4];
  const float* wk  = (const float*)d_in[5];  const float* bk  = (const float*)d_in[6];
  const float* wv  = (const float*)d_in[7];  const float* bv  = (const float*)d_in[8];
  const float* nqw = (const float*)d_in[9];  const float* nkw = (const float*)d_in[10];
  // d_in[11],[12],[17]: add_q_proj + norm_added_q -> dead (context q unused)
  const float* wak = (const float*)d_in[13]; const float* bak = (const float*)d_in[14];
  const float* wav = (const float*)d_in[15]; const float* bav = (const float*)d_in[16];
  const float* nakw = (const float*)d_in[18];
  const float* wo  = (const float*)d_in[19]; const float* bo  = (const float*)d_in[20];
  // d_in[21],[22]: to_add_out -> dead
  float* out = (float*)d_out;

  char* p = (char*)d_ws;
  auto carve = [&](size_t bytes) { char* r = p; p += (bytes + 255) & ~(size_t)255; return r; };
  short* Xb   = (short*)carve((size_t)2048 * 1536 * 2);
  short* Eb   = (short*)carve((size_t)256 * 1536 * 2);
  short* Wqb  = (short*)carve((size_t)1536 * 1536 * 2);
  short* Wkb  = (short*)carve((size_t)1536 * 1536 * 2);
  short* Wvb  = (short*)carve((size_t)1536 * 1536 * 2);
  short* Wakb = (short*)carve((size_t)1536 * 1536 * 2);
  short* Wavb = (short*)carve((size_t)1536 * 1536 * 2);
  short* Wob  = (short*)carve((size_t)1536 * 1536 * 2);
  short* Qb   = (short*)carve((size_t)24 * 2048 * 64 * 2);
  short* Kb   = (short*)carve((size_t)24 * 2304 * 64 * 2);
  short* VTb  = (short*)carve((size_t)24 * 64 * 2304 * 2);
  short* AOb  = (short*)carve((size_t)2048 * 1536 * 2);

  CvtArgs ca;
  ca.s[0] = {hidden, Xb, 2048 * 1536 / 4};
  ca.s[1] = {enc,    Eb, 256 * 1536 / 4};
  ca.s[2] = {wq,  Wqb,  1536 * 1536 / 4};
  ca.s[3] = {wk,  Wkb,  1536 * 1536 / 4};
  ca.s[4] = {wv,  Wvb,  1536 * 1536 / 4};
  ca.s[5] = {wak, Wakb, 1536 * 1536 / 4};
  ca.s[6] = {wav, Wavb, 1536 * 1536 / 4};
  ca.s[7] = {wo,  Wob,  1536 * 1536 / 4};
  cvt_bf16_kernel<<<dim3(1024), dim3(256), 0, stream>>>(ca);

  GemmArgs g1;  // all five projections in one launch (z = 0..4)
  g1.c[0] = {Xb, Wqb,  bq,  nqw,     (void*)Qb,  0,    MODE_Q, 16};
  g1.c[1] = {Xb, Wkb,  bk,  nkw,     (void*)Kb,  0,    MODE_K, 16};
  g1.c[2] = {Xb, Wvb,  bv,  nullptr, (void*)VTb, 0,    MODE_V, 16};
  g1.c[3] = {Eb, Wakb, bak, nakw,    (void*)Kb,  2048, MODE_K, 2};
  g1.c[4] = {Eb, Wavb, bav, nullptr, (void*)VTb, 2048, MODE_V, 2};
  proj_gemm_kernel<<<dim3(12, 16, 5), dim3(256), 0, stream>>>(g1);

  flash_kernel<<<dim3(1536), dim3(256), 0, stream>>>(Qb, Kb, VTb, amask, AOb);

  GemmArgs g3;  // out projection -> fp32 d_out
  g3.c[0] = {AOb, Wob, bo, nullptr, (void*)out, 0, MODE_OUT, 16};
  proj_gemm_kernel<<<dim3(12, 16, 1), dim3(256), 0, stream>>>(g3);
}

// Round 6
// 292.461 us; speedup vs baseline: 1.1134x; 1.1134x over previous
//
#include <hip/hip_runtime.h>
#include <cstdint>

// ---------------------------------------------------------------------------
// AttentionAIC: dual-stream QKV proj + per-head RMSNorm + joint SDPA + out-proj
// B=1, S=2048, S_enc=256, D=1536, H=24, HD=64, T=2304.
// Context output discarded -> skip add_q_proj, encoder q-rows, to_add_out.
// R6: GEMM reverted to R4 (BK=32; BK=64 regressed). Flash is LDS-issue bound
// (R4: ~310 LDS-pipe cyc per 16qx64k unit = 56us floor): now each wave owns
// 32 q-rows (2 groups) + split-K x2, K/V fragments read once per iter and
// reused by both groups -> 0.69x LDS ops per unit. Grid 768, LDS 40KB.
// ---------------------------------------------------------------------------

typedef __attribute__((ext_vector_type(8))) short s16x8;   // 8 x bf16
typedef __attribute__((ext_vector_type(4))) float f32x4;

#define LOG2E 1.4426950408889634f

__device__ __forceinline__ short f2bf(float f) {          // RNE (epilogues)
  union { float f; uint32_t u; } v; v.f = f;
  uint32_t r = v.u + 0x7FFFu + ((v.u >> 16) & 1u);
  return (short)(r >> 16);
}
__device__ __forceinline__ short f2bf_fast(float f) {     // round-to-nearest
  union { float f; uint32_t u; } v; v.f = f;
  return (short)((v.u + 0x8000u) >> 16);
}

typedef uint32_t __attribute__((address_space(1)))* gas_u32;
typedef uint32_t __attribute__((address_space(3)))* las_u32;

// async global->LDS, 16B per lane; dest must be wave-uniform base + lane*16
__device__ __forceinline__ void gload_lds16(const short* g, short* l) {
  __builtin_amdgcn_global_load_lds((gas_u32)(g), (las_u32)(l), 16, 0, 0);
}

// ---------------------------------------------------------------------------
// fp32 -> bf16 conversion (8 segments in one launch)
// ---------------------------------------------------------------------------
struct CvtSeg { const float* src; short* dst; int n4; };
struct CvtArgs { CvtSeg s[8]; };

__global__ __launch_bounds__(256) void cvt_bf16_kernel(CvtArgs a) {
  const int stride = gridDim.x * blockDim.x;
  const int tid = blockIdx.x * blockDim.x + threadIdx.x;
  for (int i = 0; i < 8; ++i) {
    const float4* src = (const float4*)a.s[i].src;
    short* dst = a.s[i].dst;
    const int n4 = a.s[i].n4;
    for (int j = tid; j < n4; j += stride) {
      float4 v = src[j];
      short4 o;
      o.x = f2bf(v.x); o.y = f2bf(v.y); o.z = f2bf(v.z); o.w = f2bf(v.w);
      *(short4*)(dst + (size_t)j * 4) = o;
    }
  }
}

// ---------------------------------------------------------------------------
// GEMM (R4-proven): C[M,1536] = A[M,1536] @ W[1536,1536]^T (+bias), fused
// epilogues. 128x128 tile, BK=32, 4 waves (2x2), wave = 64x64 via 4x4 MFMA.
// ---------------------------------------------------------------------------
enum { MODE_Q = 0, MODE_K = 1, MODE_V = 2, MODE_OUT = 3 };

struct GemmCfg {
  const short* A;      // [M,1536] bf16
  const short* W;      // [1536,1536] bf16, row-major [N][K]
  const float* bias;   // [1536] fp32
  const float* normw;  // [64] fp32 (Q/K modes)
  void* dst;
  int toff;            // t offset for K/V (0 hidden, 2048 encoder)
  int mode;
  int mtiles;          // # of 128-row M tiles (16 hidden, 2 encoder)
};
struct GemmArgs { GemmCfg c[5]; };

__global__ __launch_bounds__(256) void proj_gemm_kernel(GemmArgs args) {
  const GemmCfg cfg = args.c[blockIdx.z];
  if ((int)blockIdx.y >= cfg.mtiles) return;
  constexpr int K = 1536;
  __shared__ short As[4096];  // [128][32]
  __shared__ short Bs[4096];  // [128][32]
  const int t = threadIdx.x;
  const int lane = t & 63;
  const int wave = t >> 6;
  const int l16 = lane & 15;
  const int quad = lane >> 4;
  const int wm = wave >> 1;
  const int wn = wave & 1;

  const short* __restrict__ Ag = cfg.A + (size_t)(blockIdx.y * 128) * K;
  const short* __restrict__ Wg = cfg.W + (size_t)(blockIdx.x * 128) * K;
  const int srow = t >> 2;          // 0..63
  const int scol = (t & 3) << 3;    // 0,8,16,24

  const f32x4 z4 = {0.f, 0.f, 0.f, 0.f};
  f32x4 acc[4][4];
#pragma unroll
  for (int i = 0; i < 4; ++i) {
#pragma unroll
    for (int j = 0; j < 4; ++j) acc[i][j] = z4;
  }

  for (int k0 = 0; k0 < K; k0 += 32) {
    gload_lds16(Ag + (size_t)srow * K + k0 + scol, As + t * 8);
    gload_lds16(Ag + (size_t)(srow + 64) * K + k0 + scol, As + 2048 + t * 8);
    gload_lds16(Wg + (size_t)srow * K + k0 + scol, Bs + t * 8);
    gload_lds16(Wg + (size_t)(srow + 64) * K + k0 + scol, Bs + 2048 + t * 8);
    __syncthreads();
    s16x8 af[4], bfr[4];
#pragma unroll
    for (int i = 0; i < 4; ++i)
      af[i] = *(const s16x8*)(As + (wm * 64 + i * 16 + l16) * 32 + quad * 8);
#pragma unroll
    for (int i = 0; i < 4; ++i)
      bfr[i] = *(const s16x8*)(Bs + (wn * 64 + i * 16 + l16) * 32 + quad * 8);
#pragma unroll
    for (int mi = 0; mi < 4; ++mi) {
#pragma unroll
      for (int ni = 0; ni < 4; ++ni)
        acc[mi][ni] = __builtin_amdgcn_mfma_f32_16x16x32_bf16(af[mi], bfr[ni], acc[mi][ni], 0, 0, 0);
    }
    __syncthreads();
  }

  // epilogue: C/D layout col=lane&15, row=quad*4+reg
  const int nbase = blockIdx.x * 128 + wn * 64;   // 64-aligned -> one head/wave
  const int mbase = blockIdx.y * 128 + wm * 64;
  const int mode = cfg.mode;
  const int h = nbase >> 6;

  float biasv[4], nwv[4];
#pragma unroll
  for (int ni = 0; ni < 4; ++ni) {
    int col = nbase + ni * 16 + l16;
    biasv[ni] = cfg.bias[col];
    nwv[ni] = (mode == MODE_Q || mode == MODE_K) ? cfg.normw[col & 63] : 0.f;
  }

#pragma unroll
  for (int mi = 0; mi < 4; ++mi) {
    float vv[4][4];
#pragma unroll
    for (int ni = 0; ni < 4; ++ni) {
#pragma unroll
      for (int r = 0; r < 4; ++r) vv[ni][r] = acc[mi][ni][r] + biasv[ni];
    }
    if (mode == MODE_Q || mode == MODE_K) {
      float ss[4];
#pragma unroll
      for (int r = 0; r < 4; ++r)
        ss[r] = vv[0][r] * vv[0][r] + vv[1][r] * vv[1][r] +
                vv[2][r] * vv[2][r] + vv[3][r] * vv[3][r];
#pragma unroll
      for (int r = 0; r < 4; ++r) {
        ss[r] += __shfl_xor(ss[r], 1);
        ss[r] += __shfl_xor(ss[r], 2);
        ss[r] += __shfl_xor(ss[r], 4);
        ss[r] += __shfl_xor(ss[r], 8);
        float rs = rsqrtf(ss[r] * (1.0f / 64.0f) + 1e-6f);
#pragma unroll
        for (int ni = 0; ni < 4; ++ni) vv[ni][r] *= rs * nwv[ni];
      }
    }
    const int row0 = mbase + mi * 16 + quad * 4;  // + r
    if (mode == MODE_Q) {
      short* Qd = (short*)cfg.dst;  // [24][2048][64]
#pragma unroll
      for (int ni = 0; ni < 4; ++ni) {
        int d = ni * 16 + l16;
#pragma unroll
        for (int r = 0; r < 4; ++r)
          Qd[((size_t)h * 2048 + row0 + r) * 64 + d] = f2bf(vv[ni][r]);
      }
    } else if (mode == MODE_K) {
      short* Kd = (short*)cfg.dst;  // [24][2304][64]
#pragma unroll
      for (int ni = 0; ni < 4; ++ni) {
        int d = ni * 16 + l16;
#pragma unroll
        for (int r = 0; r < 4; ++r)
          Kd[((size_t)h * 2304 + cfg.toff + row0 + r) * 64 + d] = f2bf(vv[ni][r]);
      }
    } else if (mode == MODE_V) {
      short* Vd = (short*)cfg.dst;  // V^T: [24][64][2304]
#pragma unroll
      for (int ni = 0; ni < 4; ++ni) {
        int d = ni * 16 + l16;
        short4 o4;
        o4.x = f2bf(vv[ni][0]); o4.y = f2bf(vv[ni][1]);
        o4.z = f2bf(vv[ni][2]); o4.w = f2bf(vv[ni][3]);
        *(short4*)(Vd + ((size_t)h * 64 + d) * 2304 + cfg.toff + row0) = o4;
      }
    } else {  // MODE_OUT: fp32 row-major [2048][1536]
      float* Od = (float*)cfg.dst;
#pragma unroll
      for (int ni = 0; ni < 4; ++ni) {
        int col = nbase + ni * 16 + l16;
#pragma unroll
        for (int r = 0; r < 4; ++r)
          Od[(size_t)(row0 + r) * 1536 + col] = vv[ni][r];
      }
    }
  }
}

// ---------------------------------------------------------------------------
// Flash attention v5: block = (64 q-rows, head). Wave w: qw=w&1 owns 32
// q-rows (two 16-row groups), ks=w>>1 owns a 1152-k stream (36 x 32-t tiles).
// Each pair (same ks) double-buffers a 32x64 K tile + 64x32 V^T tile via
// global_load_lds (source XOR-chunk swizzled); K/V MFMA fragments are read
// from LDS ONCE per iter and reused by both q-groups (the LDS-pipe is the
// bottleneck; this is 0.69x LDS ops vs R4). No online max (|s|<=8, RMSNormed
// q,k); l = P @ ones. Cross-stream (o,l) combined via LDS at the end.
// Grid 768 = 8 XCD * 3 heads * 32 qblk, XCD round-robin swizzle. LDS 40KB.
// ---------------------------------------------------------------------------
__global__ __launch_bounds__(256) void flash_kernel(
    const short* __restrict__ Q, const short* __restrict__ Kc,
    const short* __restrict__ VT, const float* __restrict__ mask,
    short* __restrict__ AO) {
  const int b = blockIdx.x;
  const int h = (b & 7) * 3 + ((b >> 3) % 3);
  const int q0 = ((b >> 3) / 3) * 64;
  const int lane = threadIdx.x & 63;
  const int wave = threadIdx.x >> 6;
  const int qw = wave & 1;   // which 32-row q half
  const int ks = wave >> 1;  // k stream
  const int l16 = lane & 15;
  const int quad = lane >> 4;

  // shorts: Kt (ks*2+buf)*2048 @0 ; Vt @8192 ; P @16384 (wave*1024+g*512)
  __shared__ __align__(16) short smem[20480];   // 40 KB

  const short* Kh = Kc + (size_t)h * 2304 * 64;
  const short* Vh = VT + (size_t)h * 64 * 2304;

  // Q fragments for this wave's two 16-row groups
  s16x8 aq0[2], aq1[2];
#pragma unroll
  for (int g = 0; g < 2; ++g) {
    const short* Qrow =
        Q + ((size_t)h * 2048 + q0 + qw * 32 + g * 16 + l16) * 64;
    aq0[g] = *(const s16x8*)(Qrow + quad * 8);
    aq1[g] = *(const s16x8*)(Qrow + quad * 8 + 32);
  }

  s16x8 ones;
#pragma unroll
  for (int i = 0; i < 8; ++i) ones[i] = (short)0x3F80;  // bf16 1.0

  const f32x4 z4 = {0.f, 0.f, 0.f, 0.f};
  f32x4 o[2][4];
#pragma unroll
  for (int g = 0; g < 2; ++g)
#pragma unroll
    for (int ni = 0; ni < 4; ++ni) o[g][ni] = z4;
  f32x4 lacc[2] = {z4, z4};
  const float SC = 0.125f * LOG2E;
  const int kbase = ks * 1152;

  auto stage = [&](int it, int buf) {
    const int kb = kbase + it * 32;
    short* kt = smem + (ks * 2 + buf) * 2048;
    short* vt = smem + 8192 + (ks * 2 + buf) * 2048;
#pragma unroll
    for (int c = 0; c < 2; ++c) {
      const int gi = c * 128 + qw * 64 + lane;
      // K tile [t=32][d=64] (8 chunks/row), src chunk = cp ^ (t&7)
      const int trow = gi >> 3, cp = gi & 7;
      gload_lds16(Kh + (size_t)(kb + trow) * 64 + ((cp ^ (trow & 7)) << 3),
                  kt + c * 1024 + qw * 512 + lane * 8);
      // V^T tile [d=64][t=32] (4 chunks/row), src chunk = cp ^ ((d>>1)&3)
      const int d = gi >> 2, cpv = gi & 3;
      gload_lds16(Vh + (size_t)d * 2304 + kb + ((cpv ^ ((d >> 1) & 3)) << 3),
                  vt + c * 1024 + qw * 512 + lane * 8);
    }
  };

  stage(0, 0);
  __syncthreads();

  for (int it = 0; it < 36; ++it) {
    const int buf = it & 1;
    if (it < 35) stage(it + 1, buf ^ 1);
    const short* kt = smem + (ks * 2 + buf) * 2048;
    const short* vt = smem + 8192 + (ks * 2 + buf) * 2048;
    const int kb = kbase + it * 32;

    // K/V fragments: read ONCE, reused by both q-groups
    s16x8 bk[2][2];
#pragma unroll
    for (int ni = 0; ni < 2; ++ni) {
      const int tt = ni * 16 + l16;
      const short* kr = kt + tt * 64;
      bk[ni][0] = *(const s16x8*)(kr + ((quad ^ (tt & 7)) << 3));
      bk[ni][1] = *(const s16x8*)(kr + (((quad + 4) ^ (tt & 7)) << 3));
    }
    s16x8 bv[4];
#pragma unroll
    for (int ni = 0; ni < 4; ++ni) {
      const int d = ni * 16 + l16;
      bv[ni] = *(const s16x8*)(vt + d * 32 + ((quad ^ ((d >> 1) & 3)) << 3));
    }
    float mvl[2];
#pragma unroll
    for (int ni = 0; ni < 2; ++ni) mvl[ni] = mask[kb + ni * 16 + l16] * LOG2E;

#pragma unroll
    for (int g = 0; g < 2; ++g) {
      short* Pg = smem + 16384 + wave * 1024 + g * 512;
#pragma unroll
      for (int ni = 0; ni < 2; ++ni) {
        f32x4 s = __builtin_amdgcn_mfma_f32_16x16x32_bf16(aq0[g], bk[ni][0], z4, 0, 0, 0);
        s = __builtin_amdgcn_mfma_f32_16x16x32_bf16(aq1[g], bk[ni][1], s, 0, 0, 0);
        const int tt = ni * 16 + l16;
        const int cc = tt >> 3;
#pragma unroll
        for (int rr = 0; rr < 4; ++rr) {
          float pv = __builtin_amdgcn_exp2f(fmaf(s[rr], SC, mvl[ni]));
          const int prow = quad * 4 + rr;
          Pg[prow * 32 + ((cc ^ ((prow >> 1) & 3)) << 3) + (tt & 7)] = f2bf_fast(pv);
        }
      }
      // P: C-layout -> A-operand (same-wave LDS roundtrip, in-order DS pipe)
      s16x8 ap = *(const s16x8*)(Pg + l16 * 32 + ((quad ^ ((l16 >> 1) & 3)) << 3));
      lacc[g] = __builtin_amdgcn_mfma_f32_16x16x32_bf16(ap, ones, lacc[g], 0, 0, 0);
#pragma unroll
      for (int ni = 0; ni < 4; ++ni)
        o[g][ni] = __builtin_amdgcn_mfma_f32_16x16x32_bf16(ap, bv[ni], o[g][ni], 0, 0, 0);
    }
    __syncthreads();   // next tile's staging landed during compute
  }

  // cross-stream combine: ks=1 dumps (o,l) to LDS (reuses K/V region), ks=0 sums
  f32x4* R = (f32x4*)smem;   // [qw*64+lane][10]
  if (ks == 1) {
    f32x4* Rw = R + (qw * 64 + lane) * 10;
#pragma unroll
    for (int g = 0; g < 2; ++g) {
#pragma unroll
      for (int ni = 0; ni < 4; ++ni) Rw[g * 5 + ni] = o[g][ni];
      Rw[g * 5 + 4] = lacc[g];
    }
  }
  __syncthreads();
  if (ks == 0) {
    const f32x4* Rw = R + (qw * 64 + lane) * 10;
#pragma unroll
    for (int g = 0; g < 2; ++g) {
#pragma unroll
      for (int ni = 0; ni < 4; ++ni) o[g][ni] += Rw[g * 5 + ni];
      f32x4 ls = lacc[g] + Rw[g * 5 + 4];
#pragma unroll
      for (int rr = 0; rr < 4; ++rr) {
        float inv = 1.0f / ls[rr];
        int tq = q0 + qw * 32 + g * 16 + quad * 4 + rr;
#pragma unroll
        for (int ni = 0; ni < 4; ++ni)
          AO[(size_t)tq * 1536 + h * 64 + ni * 16 + l16] = f2bf(o[g][ni][rr] * inv);
      }
    }
  }
}

// ---------------------------------------------------------------------------
extern "C" void kernel_launch(void* const* d_in, const int* in_sizes, int n_in,
                              void* d_out, int out_size, void* d_ws, size_t ws_size,
                              hipStream_t stream) {
  (void)in_sizes; (void)n_in; (void)out_size; (void)ws_size;
  const float* hidden = (const float*)d_in[0];
  const float* enc    = (const float*)d_in[1];
  const float* amask  = (const float*)d_in[2];
  const float* wq  = (const float*)d_in[3];  const float* bq  = (const float*)d_in[4];
  const float* wk  = (const float*)d_in[5];  const float* bk  = (const float*)d_in[6];
  const float* wv  = (const float*)d_in[7];  const float* bv  = (const float*)d_in[8];
  const float* nqw = (const float*)d_in[9];  const float* nkw = (const float*)d_in[10];
  // d_in[11],[12],[17]: add_q_proj + norm_added_q -> dead (context q unused)
  const float* wak = (const float*)d_in[13]; const float* bak = (const float*)d_in[14];
  const float* wav = (const float*)d_in[15]; const float* bav = (const float*)d_in[16];
  const float* nakw = (const float*)d_in[18];
  const float* wo  = (const float*)d_in[19]; const float* bo  = (const float*)d_in[20];
  // d_in[21],[22]: to_add_out -> dead
  float* out = (float*)d_out;

  char* p = (char*)d_ws;
  auto carve = [&](size_t bytes) { char* r = p; p += (bytes + 255) & ~(size_t)255; return r; };
  short* Xb   = (short*)carve((size_t)2048 * 1536 * 2);
  short* Eb   = (short*)carve((size_t)256 * 1536 * 2);
  short* Wqb  = (short*)carve((size_t)1536 * 1536 * 2);
  short* Wkb  = (short*)carve((size_t)1536 * 1536 * 2);
  short* Wvb  = (short*)carve((size_t)1536 * 1536 * 2);
  short* Wakb = (short*)carve((size_t)1536 * 1536 * 2);
  short* Wavb = (short*)carve((size_t)1536 * 1536 * 2);
  short* Wob  = (short*)carve((size_t)1536 * 1536 * 2);
  short* Qb   = (short*)carve((size_t)24 * 2048 * 64 * 2);
  short* Kb   = (short*)carve((size_t)24 * 2304 * 64 * 2);
  short* VTb  = (short*)carve((size_t)24 * 64 * 2304 * 2);
  short* AOb  = (short*)carve((size_t)2048 * 1536 * 2);

  CvtArgs ca;
  ca.s[0] = {hidden, Xb, 2048 * 1536 / 4};
  ca.s[1] = {enc,    Eb, 256 * 1536 / 4};
  ca.s[2] = {wq,  Wqb,  1536 * 1536 / 4};
  ca.s[3] = {wk,  Wkb,  1536 * 1536 / 4};
  ca.s[4] = {wv,  Wvb,  1536 * 1536 / 4};
  ca.s[5] = {wak, Wakb, 1536 * 1536 / 4};
  ca.s[6] = {wav, Wavb, 1536 * 1536 / 4};
  ca.s[7] = {wo,  Wob,  1536 * 1536 / 4};
  cvt_bf16_kernel<<<dim3(1024), dim3(256), 0, stream>>>(ca);

  GemmArgs g1;  // all five projections in one launch (z = 0..4)
  g1.c[0] = {Xb, Wqb,  bq,  nqw,     (void*)Qb,  0,    MODE_Q, 16};
  g1.c[1] = {Xb, Wkb,  bk,  nkw,     (void*)Kb,  0,    MODE_K, 16};
  g1.c[2] = {Xb, Wvb,  bv,  nullptr, (void*)VTb, 0,    MODE_V, 16};
  g1.c[3] = {Eb, Wakb, bak, nakw,    (void*)Kb,  2048, MODE_K, 2};
  g1.c[4] = {Eb, Wavb, bav, nullptr, (void*)VTb, 2048, MODE_V, 2};
  proj_gemm_kernel<<<dim3(12, 16, 5), dim3(256), 0, stream>>>(g1);

  flash_kernel<<<dim3(768), dim3(256), 0, stream>>>(Qb, Kb, VTb, amask, AOb);

  GemmArgs g3;  // out projection -> fp32 d_out
  g3.c[0] = {AOb, Wob, bo, nullptr, (void*)out, 0, MODE_OUT, 16};
  proj_gemm_kernel<<<dim3(12, 16, 1), dim3(256), 0, stream>>>(g3);
}